// Round 2
// baseline (1300.409 us; speedup 1.0000x reference)
//
#include <hip/hip_runtime.h>
#include <stdint.h>
#include <math.h>

// ---------------- problem constants ----------------
#define B_    2048
#define H_    1024
#define E_    1024
#define V_    50257
#define VPAD  50304   // 393 * 128

typedef unsigned short ushort_t;
typedef __attribute__((ext_vector_type(8))) __bf16 bf16x8;
typedef __attribute__((ext_vector_type(8))) unsigned short ushort8;
typedef __attribute__((ext_vector_type(4))) float f32x4;

static __device__ __forceinline__ ushort_t f2bf(float f) {
  union { float f; uint32_t u; } v; v.f = f;
  uint32_t u = v.u;
  return (ushort_t)((u + 0x7fffu + ((u >> 16) & 1u)) >> 16);
}

typedef const __attribute__((address_space(1))) void* gas_ptr;
typedef __attribute__((address_space(3))) void* las_ptr;
static __device__ __forceinline__ void gload16(const void* g, void* l) {
  __builtin_amdgcn_global_load_lds((gas_ptr)g, (las_ptr)l, 16, 0, 0);
}

// ---------------- embedding gather -> bf16 ----------------
// grid 1024 x 256 threads, 8 elems/thread
__global__ void k_gather(const int* __restrict__ x, const float* __restrict__ emb,
                         ushort_t* __restrict__ xe) {
  int t = blockIdx.x * 256 + threadIdx.x;      // 0 .. B*E/8
  int b = t >> 7;                               // 128 threads per row
  int e8 = (t & 127) * 8;
  const float* src = emb + (size_t)x[b] * E_ + e8;
  float4 f0 = *(const float4*)(src);
  float4 f1 = *(const float4*)(src + 4);
  ushort8 o;
  o[0] = f2bf(f0.x); o[1] = f2bf(f0.y); o[2] = f2bf(f0.z); o[3] = f2bf(f0.w);
  o[4] = f2bf(f1.x); o[5] = f2bf(f1.y); o[6] = f2bf(f1.z); o[7] = f2bf(f1.w);
  *(ushort8*)(xe + (size_t)t * 8) = o;
}

// ---------------- batched f32 -> bf16 convert ----------------
struct CvtArgs {
  const float* src[8];
  ushort_t*    dst[8];
  int          n[8];
};
__global__ void k_convert(CvtArgs a) {
  int seg = blockIdx.y;
  const float* src = a.src[seg];
  ushort_t* dst = a.dst[seg];
  int n = a.n[seg];
  int stride = gridDim.x * 256 * 4;
  for (int i = (blockIdx.x * 256 + threadIdx.x) * 4; i < n; i += stride) {
    float4 f = *(const float4*)(src + i);
    ushort4 o;
    o.x = f2bf(f.x); o.y = f2bf(f.y); o.z = f2bf(f.z); o.w = f2bf(f.w);
    *(ushort4*)(dst + i) = o;
  }
}

// ---------------- Wy f32 -> bf16 with zero pad rows ----------------
// grid = VPAD blocks, 256 threads, 4 elems/thread (one row per block)
__global__ void k_cvt_wy(const float* __restrict__ Wy, ushort_t* __restrict__ dst) {
  int row = blockIdx.x;
  int c4 = threadIdx.x * 4;
  ushort4 o;
  if (row < V_) {
    float4 f = *(const float4*)(Wy + (size_t)row * H_ + c4);
    o.x = f2bf(f.x); o.y = f2bf(f.y); o.z = f2bf(f.z); o.w = f2bf(f.w);
  } else {
    o.x = 0; o.y = 0; o.z = 0; o.w = 0;
  }
  *(ushort4*)(dst + (size_t)row * H_ + c4) = o;
}

// ---------------- c gate elementwise ----------------
// i = f = tanh(G1 + bhi + bhc); g = tanh(G2 + bhc); c_new = i*(c + g)
__global__ void k_cgate(const float* __restrict__ G1, const float* __restrict__ G2,
                        const float* __restrict__ bhi, const float* __restrict__ bhc,
                        const float* __restrict__ c,
                        float* __restrict__ cnew, ushort_t* __restrict__ cnew_bf) {
  int i = blockIdx.x * 256 + threadIdx.x;   // B*H threads
  int col = i & (H_ - 1);
  float pre1 = G1[i] + bhi[col] + bhc[col];
  float tif = tanhf(pre1);
  float pre2 = G2[i] + bhc[col];
  float gg = tanhf(pre2);
  float cn = tif * (c[i] + gg);
  cnew[i] = cn;
  cnew_bf[i] = f2bf(cn);
}

// ---------------- GEMM: out[M,N] = sum_p A_p @ W_p^T ----------------
// A_p: [2048, 1024] bf16 row-major; W_p: [N, 1024] bf16 row-major.
// 128x128 tile, BK=64, 4 waves each owning 64x64 (4x4 frags of 16x16x32 MFMA).
// Layout-safe: A and B fragments both use mu(g,i) = g*8+i within each 32-k window,
// so the MFMA dot product is exact for any HW k-permutation (operands mirrored).
#define BM 128
#define BN 128
#define BK 64

template<int NP, int EPI>
__global__ __launch_bounds__(256) void k_gemm(
    const ushort_t* __restrict__ A0, const ushort_t* __restrict__ A1, const ushort_t* __restrict__ A2,
    const ushort_t* __restrict__ W0, const ushort_t* __restrict__ W1, const ushort_t* __restrict__ W2,
    float* __restrict__ out, int ldo,
    const float* __restrict__ g3a, const float* __restrict__ bho,
    const float* __restrict__ cnew, float* __restrict__ hnew, ushort_t* __restrict__ hnew_bf,
    const float* __restrict__ by) {
  __shared__ ushort_t As[BM * BK];
  __shared__ ushort_t Bs[BN * BK];

  const int tid = threadIdx.x;
  const int l   = tid & 63;
  const int wid = tid >> 6;          // 0..3
  const int wr  = wid >> 1, wc = wid & 1;
  const int g   = l >> 4, lo = l & 15;
  const int bm  = blockIdx.x, bn = blockIdx.y;

  f32x4 acc[4][4] = {};

  const int NK = NP * (1024 / BK);   // 16 K-tiles per pair

  for (int kt = 0; kt < NK; ++kt) {
    const int p  = kt >> 4;
    const int ko = (kt & 15) * BK;
    const ushort_t* Ap = (NP == 1 || p == 0) ? A0 : (p == 1 ? A1 : A2);
    const ushort_t* Wp = (NP == 1 || p == 0) ? W0 : (p == 1 ? W1 : W2);

    // stage 128x64 bf16 tiles; LDS dest is wave-uniform base + lane*16
#pragma unroll
    for (int j = 0; j < 4; ++j) {
      int S = tid + 256 * j;          // slot = row*8 + col8
      int r = S >> 3;
      int c8 = (S & 7) * 8;
      int ldsbase = (wid * 64 + 256 * j) * 8;   // ushort elems, wave-uniform
      gload16(Ap + (size_t)(bm * BM + r) * 1024 + ko + c8, As + ldsbase);
      gload16(Wp + (size_t)(bn * BN + r) * 1024 + ko + c8, Bs + ldsbase);
    }
    __syncthreads();

#pragma unroll
    for (int kk = 0; kk < 2; ++kk) {
      bf16x8 a[4], b[4];
#pragma unroll
      for (int m = 0; m < 4; ++m)
        a[m] = *(const bf16x8*)&As[(wr * 64 + m * 16 + lo) * BK + kk * 32 + g * 8];
#pragma unroll
      for (int n = 0; n < 4; ++n)
        b[n] = *(const bf16x8*)&Bs[(wc * 64 + n * 16 + lo) * BK + kk * 32 + g * 8];
#pragma unroll
      for (int m = 0; m < 4; ++m)
#pragma unroll
        for (int n = 0; n < 4; ++n)
          acc[m][n] = __builtin_amdgcn_mfma_f32_16x16x32_bf16(a[m], b[n], acc[m][n], 0, 0, 0);
    }
    __syncthreads();
  }

  // epilogue: D row = (l>>4)*4 + reg, col = l&15  (HW-verified layout)
  const int row0 = bm * BM + wr * 64;
  const int col0 = bn * BN + wc * 64;
#pragma unroll
  for (int m = 0; m < 4; ++m) {
#pragma unroll
    for (int n = 0; n < 4; ++n) {
#pragma unroll
      for (int r = 0; r < 4; ++r) {
        int row = row0 + m * 16 + g * 4 + r;
        int col = col0 + n * 16 + lo;
        float vacc = acc[m][n][r];
        if (EPI == 0) {
          out[(size_t)row * ldo + col] = vacc;
        } else if (EPI == 1) {
          size_t idx = (size_t)row * H_ + col;
          float pre = vacc + g3a[idx] + 2.0f * bho[col];
          float o = tanhf(pre);
          float hv = o * tanhf(cnew[idx]);
          hnew[idx] = hv;
          hnew_bf[idx] = f2bf(hv);
        } else {  // EPI == 2: logits with +by, N guard
          if (col < V_) out[(size_t)row * V_ + col] = vacc + by[col];
        }
      }
    }
  }
}

// ---------------- launch ----------------
extern "C" void kernel_launch(void* const* d_in, const int* in_sizes, int n_in,
                              void* d_out, int out_size, void* d_ws, size_t ws_size,
                              hipStream_t stream) {
  const int*   x   = (const int*)d_in[0];
  const float* h   = (const float*)d_in[1];
  const float* c   = (const float*)d_in[2];
  const float* emb = (const float*)d_in[3];
  const float* Wxi = (const float*)d_in[4];
  const float* Whi = (const float*)d_in[5];
  const float* bhi = (const float*)d_in[6];
  const float* Wxc = (const float*)d_in[7];
  const float* Whc = (const float*)d_in[8];
  const float* bhc = (const float*)d_in[9];
  const float* Wxo = (const float*)d_in[10];
  const float* Who = (const float*)d_in[11];
  const float* bho = (const float*)d_in[12];
  const float* Wy  = (const float*)d_in[13];
  const float* by  = (const float*)d_in[14];

  float* logits = (float*)d_out;
  float* hnew   = logits + (size_t)B_ * V_;
  float* cnew   = hnew + (size_t)B_ * H_;

  char* ws = (char*)d_ws;
  size_t off = 0;
  auto alloc = [&](size_t bytes) {
    char* p = ws + off;
    off += (bytes + 255) & ~(size_t)255;
    return p;
  };
  ushort_t* xe_bf  = (ushort_t*)alloc((size_t)B_ * E_ * 2);
  ushort_t* h_bf   = (ushort_t*)alloc((size_t)B_ * H_ * 2);
  ushort_t* c_bf   = (ushort_t*)alloc((size_t)B_ * H_ * 2);
  ushort_t* Wxi_bf = (ushort_t*)alloc((size_t)H_ * E_ * 2);
  ushort_t* Whi_bf = (ushort_t*)alloc((size_t)H_ * H_ * 2);
  ushort_t* Whc_bf = (ushort_t*)alloc((size_t)H_ * H_ * 2);
  ushort_t* Wxc_bf = (ushort_t*)alloc((size_t)H_ * E_ * 2);
  ushort_t* Wxo_bf = (ushort_t*)alloc((size_t)H_ * E_ * 2);
  ushort_t* Who_bf = (ushort_t*)alloc((size_t)H_ * H_ * 2);
  ushort_t* Wy_bf  = (ushort_t*)alloc((size_t)VPAD * H_ * 2);
  float*    G1     = (float*)alloc((size_t)B_ * H_ * 4);
  float*    G2     = (float*)alloc((size_t)B_ * H_ * 4);
  float*    G3     = (float*)alloc((size_t)B_ * H_ * 4);
  ushort_t* cn_bf  = (ushort_t*)alloc((size_t)B_ * H_ * 2);
  ushort_t* hn_bf  = (ushort_t*)alloc((size_t)B_ * H_ * 2);
  (void)ws_size; (void)in_sizes; (void)n_in; (void)out_size;

  // 1) gather + convert
  k_gather<<<dim3((B_ * E_) / (256 * 8)), 256, 0, stream>>>(x, emb, xe_bf);
  CvtArgs ca;
  ca.src[0] = h;   ca.dst[0] = h_bf;   ca.n[0] = B_ * H_;
  ca.src[1] = c;   ca.dst[1] = c_bf;   ca.n[1] = B_ * H_;
  ca.src[2] = Wxi; ca.dst[2] = Wxi_bf; ca.n[2] = H_ * E_;
  ca.src[3] = Whi; ca.dst[3] = Whi_bf; ca.n[3] = H_ * H_;
  ca.src[4] = Whc; ca.dst[4] = Whc_bf; ca.n[4] = H_ * H_;
  ca.src[5] = Wxc; ca.dst[5] = Wxc_bf; ca.n[5] = H_ * E_;
  ca.src[6] = Wxo; ca.dst[6] = Wxo_bf; ca.n[6] = H_ * E_;
  ca.src[7] = Who; ca.dst[7] = Who_bf; ca.n[7] = H_ * H_;
  k_convert<<<dim3(512, 8), 256, 0, stream>>>(ca);
  k_cvt_wy<<<dim3(VPAD), 256, 0, stream>>>(Wy, Wy_bf);

  // 2) gate GEMMs (raw pre-activations, biases added later)
  // G1 = xe@Wxi^T + h@Whi^T + c@Whc^T
  k_gemm<3, 0><<<dim3(16, 8), 256, 0, stream>>>(
      xe_bf, h_bf, c_bf, Wxi_bf, Whi_bf, Whc_bf,
      G1, H_, nullptr, nullptr, nullptr, nullptr, nullptr, nullptr);
  // G2 = xe@Wxc^T + h@Whc^T
  k_gemm<2, 0><<<dim3(16, 8), 256, 0, stream>>>(
      xe_bf, h_bf, nullptr, Wxc_bf, Whc_bf, nullptr,
      G2, H_, nullptr, nullptr, nullptr, nullptr, nullptr, nullptr);
  // G3 = xe@Wxo^T + h@Who^T
  k_gemm<2, 0><<<dim3(16, 8), 256, 0, stream>>>(
      xe_bf, h_bf, nullptr, Wxo_bf, Who_bf, nullptr,
      G3, H_, nullptr, nullptr, nullptr, nullptr, nullptr, nullptr);

  // 3) c_new elementwise
  k_cgate<<<dim3((B_ * H_) / 256), 256, 0, stream>>>(G1, G2, bhi, bhc, c, cnew, cn_bf);

  // 4) o gate + h_new fused into c_new@Who^T GEMM
  k_gemm<1, 1><<<dim3(16, 8), 256, 0, stream>>>(
      cn_bf, nullptr, nullptr, Who_bf, nullptr, nullptr,
      nullptr, 0, G3, bho, cnew, hnew, hn_bf, nullptr);

  // 5) logits = h_new@Wy^T + by
  k_gemm<1, 2><<<dim3(16, VPAD / BN), 256, 0, stream>>>(
      hn_bf, nullptr, nullptr, Wy_bf, nullptr, nullptr,
      logits, V_, nullptr, nullptr, nullptr, nullptr, nullptr, by);
}